// Round 2
// baseline (458.747 us; speedup 1.0000x reference)
//
#include <hip/hip_runtime.h>
#include <math.h>

#define PI2_6f 1.64493406684822643647f

__device__ __forceinline__ float polevlA(float w) {
    float y = 4.65128586073990045278e-5f;
    y = fmaf(y, w, 7.31589045238094711071e-3f);
    y = fmaf(y, w, 1.33847639578309018650e-1f);
    y = fmaf(y, w, 8.79691311754530315341e-1f);
    y = fmaf(y, w, 2.71149851196553469920e0f);
    y = fmaf(y, w, 4.25697156008121755724e0f);
    y = fmaf(y, w, 3.29771340985225106936e0f);
    y = fmaf(y, w, 1.00000000000000000126e0f);
    return y;
}

__device__ __forceinline__ float polevlB(float w) {
    float y = 6.90990488912553276999e-4f;
    y = fmaf(y, w, 2.54043763932544379113e-2f);
    y = fmaf(y, w, 2.82974860602568089943e-1f);
    y = fmaf(y, w, 1.41172597751831069617e0f);
    y = fmaf(y, w, 3.63800533345137075418e0f);
    y = fmaf(y, w, 5.03278880143316990390e0f);
    y = fmaf(y, w, 4.92478529773146006102e0f);
    y = fmaf(y, w, 1.00000000000000000000e0f);
    return y;
}

__device__ __forceinline__ float spencef(float x) {
    // Range reduction (branchless, mirrors Cephes/reference semantics).
    // Note: the `hi` branch needs 1/xt, but hi implies !big so xt==x there;
    // the `big` branch needs 1/x. One division serves both.
    const float r = 1.0f / x;                 // inf at x==0, unused there
    const bool big = x > 2.0f;
    const float xt = big ? r : x;
    const bool hi = xt > 1.5f;                // only possible when !big
    const bool lo = xt < 0.5f;

    float w = xt - 1.0f;
    w = lo ? -xt : w;
    w = hi ? (r - 1.0f) : w;                  // 1/xt - 1 == r - 1 when hi

    float y = -w * polevlA(w) / polevlB(w);

    const float log_xt   = logf(xt > 0.0f ? xt : 1.0f);
    const float log_1mxt = logf(xt < 1.0f ? 1.0f - xt : 1.0f);

    // flag1 correction (lo), then flag2 correction (big|hi), as in Cephes
    y = lo ? (PI2_6f - log_xt * log_1mxt - y) : y;
    y = (big || hi) ? (-0.5f * log_xt * log_xt - y) : y;

    // exact special points / domain
    y = (x == 0.0f) ? PI2_6f : y;
    y = (x == 1.0f) ? 0.0f : y;
    y = (x < 0.0f) ? __int_as_float(0x7fc00000) : y;  // NaN
    return y;
}

__global__ void __launch_bounds__(256)
spence_kernel(const float4* __restrict__ in, float4* __restrict__ out, int n4) {
    const int stride = gridDim.x * blockDim.x;
    for (int i = blockIdx.x * blockDim.x + threadIdx.x; i < n4; i += stride) {
        const float4 v = in[i];
        float4 o;
        o.x = spencef(v.x);
        o.y = spencef(v.y);
        o.z = spencef(v.z);
        o.w = spencef(v.w);
        out[i] = o;
    }
}

__global__ void __launch_bounds__(256)
spence_tail_kernel(const float* __restrict__ in, float* __restrict__ out,
                   int start, int n) {
    const int i = start + blockIdx.x * blockDim.x + threadIdx.x;
    if (i < n) out[i] = spencef(in[i]);
}

extern "C" void kernel_launch(void* const* d_in, const int* in_sizes, int n_in,
                              void* d_out, int out_size, void* d_ws, size_t ws_size,
                              hipStream_t stream) {
    const float* in = (const float*)d_in[0];
    float* out = (float*)d_out;
    const int n = in_sizes[0];
    const int n4 = n / 4;

    const int block = 256;
    int grid = (n4 + block - 1) / block;
    if (grid > 2048) grid = 2048;
    if (grid < 1) grid = 1;

    spence_kernel<<<grid, block, 0, stream>>>(
        (const float4*)in, (float4*)out, n4);

    const int tail_start = n4 * 4;
    const int tail = n - tail_start;
    if (tail > 0) {
        spence_tail_kernel<<<(tail + block - 1) / block, block, 0, stream>>>(
            in, out, tail_start, n);
    }
}

// Round 4
// 435.251 us; speedup vs baseline: 1.0540x; 1.0540x over previous
//
#include <hip/hip_runtime.h>
#include <math.h>

#define PI2_6f 1.64493406684822643647f
#define LN2f   0.69314718055994530942f

// fast ln(x): single v_log_f32 (log2) * ln2. ~1 ulp of log2.
__device__ __forceinline__ float fast_log(float x) {
    return __builtin_amdgcn_logf(x) * LN2f;
}

// fast 1/x: single v_rcp_f32, ~1 ulp.
__device__ __forceinline__ float fast_rcp(float x) {
    return __builtin_amdgcn_rcpf(x);
}

__device__ __forceinline__ float polevlA(float w) {
    float y = 4.65128586073990045278e-5f;
    y = fmaf(y, w, 7.31589045238094711071e-3f);
    y = fmaf(y, w, 1.33847639578309018650e-1f);
    y = fmaf(y, w, 8.79691311754530315341e-1f);
    y = fmaf(y, w, 2.71149851196553469920e0f);
    y = fmaf(y, w, 4.25697156008121755724e0f);
    y = fmaf(y, w, 3.29771340985225106936e0f);
    y = fmaf(y, w, 1.00000000000000000126e0f);
    return y;
}

__device__ __forceinline__ float polevlB(float w) {
    float y = 6.90990488912553276999e-4f;
    y = fmaf(y, w, 2.54043763932544379113e-2f);
    y = fmaf(y, w, 2.82974860602568089943e-1f);
    y = fmaf(y, w, 1.41172597751831069617e0f);
    y = fmaf(y, w, 3.63800533345137075418e0f);
    y = fmaf(y, w, 5.03278880143316990390e0f);
    y = fmaf(y, w, 4.92478529773146006102e0f);
    y = fmaf(y, w, 1.00000000000000000000e0f);
    return y;
}

__device__ __forceinline__ float spencef(float x) {
    // Range reduction (branchless, mirrors Cephes/reference semantics).
    // `hi` implies !big so xt==x there; `big` needs 1/x. One rcp serves both.
    const float r = fast_rcp(x);              // inf at x==0, unused there
    const bool big = x > 2.0f;
    const float xt = big ? r : x;
    const bool hi = xt > 1.5f;                // only possible when !big
    const bool lo = xt < 0.5f;

    float w = xt - 1.0f;
    w = lo ? -xt : w;
    w = hi ? (r - 1.0f) : w;                  // 1/xt - 1 == r - 1 when hi

    const float y_poly = -w * polevlA(w) * fast_rcp(polevlB(w));

    const float log_xt   = fast_log(xt > 0.0f ? xt : 1.0f);
    const float log_1mxt = fast_log(xt < 1.0f ? 1.0f - xt : 1.0f);

    // flag1 correction (lo), then flag2 correction (big|hi), as in Cephes
    float y = y_poly;
    y = lo ? (PI2_6f - log_xt * log_1mxt - y) : y;
    y = (big || hi) ? (-0.5f * log_xt * log_xt - y) : y;

    // exact special points / domain
    y = (x == 0.0f) ? PI2_6f : y;
    y = (x == 1.0f) ? 0.0f : y;
    y = (x < 0.0f) ? __int_as_float(0x7fc00000) : y;  // NaN
    return y;
}

__global__ void __launch_bounds__(256)
spence_kernel(const float4* __restrict__ in, float4* __restrict__ out, int n4) {
    const int stride = gridDim.x * blockDim.x;
    for (int i = blockIdx.x * blockDim.x + threadIdx.x; i < n4; i += stride) {
        const float4 v = in[i];
        float4 o;
        o.x = spencef(v.x);
        o.y = spencef(v.y);
        o.z = spencef(v.z);
        o.w = spencef(v.w);
        out[i] = o;
    }
}

__global__ void __launch_bounds__(256)
spence_tail_kernel(const float* __restrict__ in, float* __restrict__ out,
                   int start, int n) {
    const int i = start + blockIdx.x * blockDim.x + threadIdx.x;
    if (i < n) out[i] = spencef(in[i]);
}

extern "C" void kernel_launch(void* const* d_in, const int* in_sizes, int n_in,
                              void* d_out, int out_size, void* d_ws, size_t ws_size,
                              hipStream_t stream) {
    const float* in = (const float*)d_in[0];
    float* out = (float*)d_out;
    const int n = in_sizes[0];
    const int n4 = n / 4;

    const int block = 256;
    int grid = (n4 + block - 1) / block;
    if (grid > 2048) grid = 2048;
    if (grid < 1) grid = 1;

    spence_kernel<<<grid, block, 0, stream>>>(
        (const float4*)in, (float4*)out, n4);

    const int tail_start = n4 * 4;
    const int tail = n - tail_start;
    if (tail > 0) {
        spence_tail_kernel<<<(tail + block - 1) / block, block, 0, stream>>>(
            in, out, tail_start, n);
    }
}